// Round 5
// baseline (116.942 us; speedup 1.0000x reference)
//
#include <hip/hip_runtime.h>

#define NPTS 8192
#define BATCH 4
#define BLOCK 256
#define NQ 4                   // queries per thread
#define QPB (BLOCK * NQ)       // 1024 queries per block
#define QBLOCKS (NPTS / QPB)   // 8
#define GROUPS 16              // target groups (partial-min slots per query)
#define GRP_SHIFT 4
#define TPB (NPTS / GROUPS)    // 512 targets per block
#define LDSPTS TPB

// ---------------------------------------------------------------------------
// chamfer: grid (QBLOCKS*GROUPS, BATCH, 2) = 1024 blocks (4 waves/SIMD).
// R5: R4's structure saturated the VALU issue port (VALUBusy ~100%) --
// the R0-R3 idle is solved by 4 waves/SIMD + independent scalar chains.
// But R4's VGPR_Count=28 exposed codegen sabotage: the working set needs
// ~42 regs, and squeezing to 28 (which gains ZERO occupancy vs 42 -- both
// allow 8 waves/EU) forced split b128 reads + remat + mov traffic = ~2x
// instruction bloat (busy 29 us -> 52 us). R5 pins t0/t1 in VGPRs with an
// empty asm constraint after the LDS load and phase-groups the 8
// independent FMA chains (static-index d0[]/d1[] arrays) so the natural
// schedule has no dependent stalls. launch_bounds(256,4) caps VGPR at 128.
// Expected: instruction count back to model (~15k cy/wave), chamfer ~28 us.
// LDS: tgt[t] = {x, y, z, |q|^2}; wave-uniform b128 broadcast reads.
// Plain partial-min stores per (query, group); no atomics, no memset.
// Block (0,0,0) zeroes out[0]. Workspace: 2*B*GROUPS*NPTS floats = 4 MiB.
// ---------------------------------------------------------------------------
__global__ __launch_bounds__(256, 4) void chamfer_kernel(
    const float* __restrict__ x, const float* __restrict__ y,
    float* __restrict__ mins, float* __restrict__ out) {
    __shared__ float4 tgt[LDSPTS];

    if (blockIdx.x == 0 && blockIdx.y == 0 && blockIdx.z == 0 && threadIdx.x == 0)
        out[0] = 0.0f;

    const int dir = blockIdx.z;
    const int b = blockIdx.y;
    const int g = blockIdx.x & (GROUPS - 1);
    const int qb = blockIdx.x >> GRP_SHIFT;

    const float* pts = dir ? y : x;  // query set
    const float* oth = dir ? x : y;  // target set

    // stage 512 targets: each thread owns two consecutive points (24 B read)
    {
        const int t = threadIdx.x;
        const float* q = oth + ((size_t)b * NPTS + g * TPB + 2 * t) * 3;
        const float qx0 = q[0], qy0 = q[1], qz0 = q[2];
        const float qx1 = q[3], qy1 = q[4], qz1 = q[5];
        const float sq0 = fmaf(qz0, qz0, fmaf(qy0, qy0, qx0 * qx0));
        const float sq1 = fmaf(qz1, qz1, fmaf(qy1, qy1, qx1 * qx1));
        tgt[2 * t]     = (float4){qx0, qy0, qz0, sq0};
        tgt[2 * t + 1] = (float4){qx1, qy1, qz1, sq1};
    }

    // query splats: -2*p per component (scalar, 3 regs/query), |p|^2 folded
    // in at the end.
    float nx[NQ], ny[NQ], nz[NQ], sp[NQ], best[NQ];
    const int qbase = b * NPTS + qb * QPB + (int)threadIdx.x;
#pragma unroll
    for (int k = 0; k < NQ; ++k) {
        const float* p = pts + (size_t)(qbase + k * BLOCK) * 3;
        const float px = p[0], py = p[1], pz = p[2];
        nx[k] = -2.0f * px;
        ny[k] = -2.0f * py;
        nz[k] = -2.0f * pz;
        sp[k] = fmaf(pz, pz, fmaf(py, py, px * px));
        best[k] = 3.0e38f;
    }

    __syncthreads();

#pragma unroll 2
    for (int j = 0; j < TPB; j += 2) {
        float4 t0 = tgt[j];
        float4 t1 = tgt[j + 1];
        // Pin the staged pair in VGPRs: stops the scheduler from splitting
        // the b128 reads / rematerializing components to shave registers
        // (R4: VGPR=28 < working set -> ~2x instruction bloat).
        asm volatile("" : "+v"(t0.x), "+v"(t0.y), "+v"(t0.z), "+v"(t0.w),
                          "+v"(t1.x), "+v"(t1.y), "+v"(t1.z), "+v"(t1.w));
        float d0[NQ], d1[NQ];
        // phase-grouped: 8 independent chains, no dependent back-to-back ops
#pragma unroll
        for (int k = 0; k < NQ; ++k) {
            d0[k] = fmaf(nx[k], t0.x, t0.w);
            d1[k] = fmaf(nx[k], t1.x, t1.w);
        }
#pragma unroll
        for (int k = 0; k < NQ; ++k) {
            d0[k] = fmaf(ny[k], t0.y, d0[k]);
            d1[k] = fmaf(ny[k], t1.y, d1[k]);
        }
#pragma unroll
        for (int k = 0; k < NQ; ++k) {
            d0[k] = fmaf(nz[k], t0.z, d0[k]);
            d1[k] = fmaf(nz[k], t1.z, d1[k]);
        }
#pragma unroll
        for (int k = 0; k < NQ; ++k)
            best[k] = fminf(best[k], fminf(d0[k], d1[k]));  // v_min3_f32
    }

    // plain coalesced stores of this group's partial min per query
    float* om = mins + ((size_t)((dir * BATCH + b) * GROUPS + g)) * NPTS +
                qb * QPB + threadIdx.x;
#pragma unroll
    for (int k = 0; k < NQ; ++k)
        om[k * BLOCK] = fmaxf(sp[k] + best[k], 0.0f);
}

// ---------------------------------------------------------------------------
// finalize: 64 blocks x 256 threads. Each thread owns 4 adjacent queries of
// one (dir,b) slice: min-reduces the 16 group partials (float4 loads,
// coalesced within each group slice), sums the 4 mins * 1/(B*N) -- the
// exact same sum tree as before. gid 0 adds the regularizer. Block reduce
// + atomicAdd into out[0].
// ---------------------------------------------------------------------------
__global__ __launch_bounds__(256) void finalize_kernel(
    const float* __restrict__ mins, const float* __restrict__ R,
    const float* __restrict__ S, const float* __restrict__ t,
    const float* __restrict__ R_gt, const float* __restrict__ S_gt,
    const float* __restrict__ t_gt, float* __restrict__ out) {
    const float4* m4 = (const float4*)mins;  // [8][GROUPS][NPTS/4]
    const int gid = blockIdx.x * 256 + (int)threadIdx.x;  // 0..16383
    const int db = gid >> 11;       // dir*BATCH+b, 0..7
    const int qi = gid & 2047;      // float4 index within slice

    float4 mn = m4[(size_t)(db * GROUPS) * (NPTS / 4) + qi];
#pragma unroll
    for (int gg = 1; gg < GROUPS; ++gg) {
        const float4 u = m4[(size_t)(db * GROUPS + gg) * (NPTS / 4) + qi];
        mn.x = fminf(mn.x, u.x);
        mn.y = fminf(mn.y, u.y);
        mn.z = fminf(mn.z, u.z);
        mn.w = fminf(mn.w, u.w);
    }
    float v = (mn.x + mn.y + mn.z + mn.w) * (1.0f / (BATCH * NPTS));

    if (gid == 0) {
        float acc = 0.0f;
        for (int b = 0; b < BATCH; ++b)
            for (int i = 0; i < 3; ++i)
                for (int k = 0; k < 3; ++k) {
                    float s = 0.0f;
                    for (int j = 0; j < 3; ++j)
                        s += R_gt[b * 9 + j * 3 + i] * R[b * 9 + j * 3 + k];
                    s -= (i == k) ? 1.0f : 0.0f;
                    acc += s * s;
                }
        for (int d = 0; d < 3; ++d)  // jnp.diagonal(S, axis1=0, axis2=1)
            for (int a = 0; a < 3; ++a) {
                const float diff = S[d * 9 + d * 3 + a] - S_gt[d * 9 + d * 3 + a];
                acc += diff * diff;
            }
        for (int b = 0; b < BATCH; ++b)
            for (int k = 0; k < 3; ++k) {
                const float diff = t[b * 3 + k] - t_gt[b * 3 + k];
                acc += diff * diff;
            }
        v += acc;
    }

    // block reduction: 4 waves of 64
    for (int off = 32; off; off >>= 1) v += __shfl_down(v, off, 64);
    __shared__ float wsum[4];
    const int lane = threadIdx.x & 63;
    const int wave = threadIdx.x >> 6;
    if (lane == 0) wsum[wave] = v;
    __syncthreads();
    if (wave == 0) {
        v = (lane < 4) ? wsum[lane] : 0.0f;
        for (int off = 2; off; off >>= 1) v += __shfl_down(v, off, 64);
        if (lane == 0) atomicAdd(out, v);
    }
}

extern "C" void kernel_launch(void* const* d_in, const int* in_sizes, int n_in,
                              void* d_out, int out_size, void* d_ws, size_t ws_size,
                              hipStream_t stream) {
    const float* x    = (const float*)d_in[0];
    const float* y    = (const float*)d_in[1];
    const float* R    = (const float*)d_in[2];
    const float* S    = (const float*)d_in[3];
    const float* t    = (const float*)d_in[4];
    const float* R_gt = (const float*)d_in[5];
    const float* S_gt = (const float*)d_in[6];
    const float* t_gt = (const float*)d_in[7];
    float* out = (float*)d_out;
    float* mins = (float*)d_ws;  // 2*BATCH*GROUPS*NPTS floats = 4 MiB

    chamfer_kernel<<<dim3(QBLOCKS * GROUPS, BATCH, 2), dim3(BLOCK), 0, stream>>>(
        x, y, mins, out);

    finalize_kernel<<<dim3(2 * BATCH * NPTS / 4 / 256), dim3(BLOCK), 0, stream>>>(
        mins, R, S, t, R_gt, S_gt, t_gt, out);
}

// Round 6
// 111.165 us; speedup vs baseline: 1.0520x; 1.0520x over previous
//
#include <hip/hip_runtime.h>

#define NPTS 8192
#define BATCH 4
#define BLOCK 256
#define NQ 4                   // queries per thread
#define QPB (BLOCK * NQ)       // 1024 queries per block
#define QBLOCKS (NPTS / QPB)   // 8
#define GROUPS 16              // target groups (partial-min slots per query)
#define GRP_SHIFT 4
#define TPB (NPTS / GROUPS)    // 512 targets per block
#define LDSPTS TPB

// ---------------------------------------------------------------------------
// chamfer: grid (QBLOCKS*GROUPS, BATCH, 2) = 1024 blocks (4 waves/SIMD).
// R6: inline-asm inner body. R4 proved the structure saturates the VALU
// port (VALUBusy ~100% at 4 waves/SIMD); R4/R5 proved the compiler
// re-schedules ANY C-level formulation into a pressure-minimal form with
// ~2x instruction bloat (VGPR pinned at 28 = exact pinned working set;
// d-chains serialized per-k). R6 removes the freedom: the whole 28-op
// body (8 v_fma + 16 v_fmac + 4 v_min3, phase-grouped so dependent ops
// are 8 instrs apart) is one asm volatile block with register-bound
// operands. Compiler keeps only LDS load scheduling + loop control.
// Model: 64 iters x ~120 cy = 7.7k cy/wave; 4 waves/SIMD -> ~25 us.
// LDS: tgt[t] = {x, y, z, |q|^2}; wave-uniform b128 broadcast reads.
// Plain partial-min stores per (query, group); no atomics, no memset.
// Block (0,0,0) zeroes out[0]. Workspace: 2*B*GROUPS*NPTS floats = 4 MiB.
// ---------------------------------------------------------------------------

// 2 targets x 4 query-chains: d = |q|^2 - 2 p.q  (sp=|p|^2 added at store).
// Phase-grouped: all 8 chains advance one component per phase -> dep
// distance 8 instructions. best updated via v_min3 at the end.
#define BODY(T0, T1)                                                          \
  {                                                                           \
    float d00, d01, d02, d03, d10, d11, d12, d13;                             \
    asm volatile(                                                             \
        "v_fma_f32 %[d00], %[nx0], %[t0x], %[t0w]\n\t"                        \
        "v_fma_f32 %[d10], %[nx0], %[t1x], %[t1w]\n\t"                        \
        "v_fma_f32 %[d01], %[nx1], %[t0x], %[t0w]\n\t"                        \
        "v_fma_f32 %[d11], %[nx1], %[t1x], %[t1w]\n\t"                        \
        "v_fma_f32 %[d02], %[nx2], %[t0x], %[t0w]\n\t"                        \
        "v_fma_f32 %[d12], %[nx2], %[t1x], %[t1w]\n\t"                        \
        "v_fma_f32 %[d03], %[nx3], %[t0x], %[t0w]\n\t"                        \
        "v_fma_f32 %[d13], %[nx3], %[t1x], %[t1w]\n\t"                        \
        "v_fmac_f32 %[d00], %[ny0], %[t0y]\n\t"                               \
        "v_fmac_f32 %[d10], %[ny0], %[t1y]\n\t"                               \
        "v_fmac_f32 %[d01], %[ny1], %[t0y]\n\t"                               \
        "v_fmac_f32 %[d11], %[ny1], %[t1y]\n\t"                               \
        "v_fmac_f32 %[d02], %[ny2], %[t0y]\n\t"                               \
        "v_fmac_f32 %[d12], %[ny2], %[t1y]\n\t"                               \
        "v_fmac_f32 %[d03], %[ny3], %[t0y]\n\t"                               \
        "v_fmac_f32 %[d13], %[ny3], %[t1y]\n\t"                               \
        "v_fmac_f32 %[d00], %[nz0], %[t0z]\n\t"                               \
        "v_fmac_f32 %[d10], %[nz0], %[t1z]\n\t"                               \
        "v_fmac_f32 %[d01], %[nz1], %[t0z]\n\t"                               \
        "v_fmac_f32 %[d11], %[nz1], %[t1z]\n\t"                               \
        "v_fmac_f32 %[d02], %[nz2], %[t0z]\n\t"                               \
        "v_fmac_f32 %[d12], %[nz2], %[t1z]\n\t"                               \
        "v_fmac_f32 %[d03], %[nz3], %[t0z]\n\t"                               \
        "v_fmac_f32 %[d13], %[nz3], %[t1z]\n\t"                               \
        "v_min3_f32 %[b0], %[b0], %[d00], %[d10]\n\t"                         \
        "v_min3_f32 %[b1], %[b1], %[d01], %[d11]\n\t"                         \
        "v_min3_f32 %[b2], %[b2], %[d02], %[d12]\n\t"                         \
        "v_min3_f32 %[b3], %[b3], %[d03], %[d13]"                             \
        : [b0] "+v"(best0), [b1] "+v"(best1), [b2] "+v"(best2),               \
          [b3] "+v"(best3), [d00] "=&v"(d00), [d01] "=&v"(d01),               \
          [d02] "=&v"(d02), [d03] "=&v"(d03), [d10] "=&v"(d10),               \
          [d11] "=&v"(d11), [d12] "=&v"(d12), [d13] "=&v"(d13)                \
        : [t0x] "v"((T0).x), [t0y] "v"((T0).y), [t0z] "v"((T0).z),            \
          [t0w] "v"((T0).w), [t1x] "v"((T1).x), [t1y] "v"((T1).y),            \
          [t1z] "v"((T1).z), [t1w] "v"((T1).w), [nx0] "v"(nx0),               \
          [nx1] "v"(nx1), [nx2] "v"(nx2), [nx3] "v"(nx3), [ny0] "v"(ny0),     \
          [ny1] "v"(ny1), [ny2] "v"(ny2), [ny3] "v"(ny3), [nz0] "v"(nz0),     \
          [nz1] "v"(nz1), [nz2] "v"(nz2), [nz3] "v"(nz3));                    \
  }

__global__ __launch_bounds__(256, 4) void chamfer_kernel(
    const float* __restrict__ x, const float* __restrict__ y,
    float* __restrict__ mins, float* __restrict__ out) {
    __shared__ float4 tgt[LDSPTS];

    if (blockIdx.x == 0 && blockIdx.y == 0 && blockIdx.z == 0 && threadIdx.x == 0)
        out[0] = 0.0f;

    const int dir = blockIdx.z;
    const int b = blockIdx.y;
    const int g = blockIdx.x & (GROUPS - 1);
    const int qb = blockIdx.x >> GRP_SHIFT;

    const float* pts = dir ? y : x;  // query set
    const float* oth = dir ? x : y;  // target set

    // stage 512 targets: each thread owns two consecutive points (24 B read)
    {
        const int t = threadIdx.x;
        const float* q = oth + ((size_t)b * NPTS + g * TPB + 2 * t) * 3;
        const float qx0 = q[0], qy0 = q[1], qz0 = q[2];
        const float qx1 = q[3], qy1 = q[4], qz1 = q[5];
        const float sq0 = fmaf(qz0, qz0, fmaf(qy0, qy0, qx0 * qx0));
        const float sq1 = fmaf(qz1, qz1, fmaf(qy1, qy1, qx1 * qx1));
        tgt[2 * t]     = (float4){qx0, qy0, qz0, sq0};
        tgt[2 * t + 1] = (float4){qx1, qy1, qz1, sq1};
    }

    // query splats: -2*p per component (scalar), |p|^2 folded in at store.
    float nx0, nx1, nx2, nx3, ny0, ny1, ny2, ny3, nz0, nz1, nz2, nz3;
    float sp0, sp1, sp2, sp3;
    float best0 = 3.0e38f, best1 = 3.0e38f, best2 = 3.0e38f, best3 = 3.0e38f;
    const int qbase = b * NPTS + qb * QPB + (int)threadIdx.x;
    {
        const float* p0 = pts + (size_t)(qbase + 0 * BLOCK) * 3;
        const float* p1 = pts + (size_t)(qbase + 1 * BLOCK) * 3;
        const float* p2 = pts + (size_t)(qbase + 2 * BLOCK) * 3;
        const float* p3 = pts + (size_t)(qbase + 3 * BLOCK) * 3;
        float px, py, pz;
        px = p0[0]; py = p0[1]; pz = p0[2];
        nx0 = -2.0f * px; ny0 = -2.0f * py; nz0 = -2.0f * pz;
        sp0 = fmaf(pz, pz, fmaf(py, py, px * px));
        px = p1[0]; py = p1[1]; pz = p1[2];
        nx1 = -2.0f * px; ny1 = -2.0f * py; nz1 = -2.0f * pz;
        sp1 = fmaf(pz, pz, fmaf(py, py, px * px));
        px = p2[0]; py = p2[1]; pz = p2[2];
        nx2 = -2.0f * px; ny2 = -2.0f * py; nz2 = -2.0f * pz;
        sp2 = fmaf(pz, pz, fmaf(py, py, px * px));
        px = p3[0]; py = p3[1]; pz = p3[2];
        nx3 = -2.0f * px; ny3 = -2.0f * py; nz3 = -2.0f * pz;
        sp3 = fmaf(pz, pz, fmaf(py, py, px * px));
    }

    __syncthreads();

    // 4 target pairs per iteration; all 8 quads loaded up front so later
    // pairs' ds_read latency hides under earlier asm bodies.
#pragma unroll 1
    for (int j = 0; j < TPB; j += 8) {
        const float4 ta = tgt[j],     tb = tgt[j + 1];
        const float4 tc = tgt[j + 2], td = tgt[j + 3];
        const float4 te = tgt[j + 4], tf = tgt[j + 5];
        const float4 tg = tgt[j + 6], th = tgt[j + 7];
        BODY(ta, tb);
        BODY(tc, td);
        BODY(te, tf);
        BODY(tg, th);
    }

    // plain coalesced stores of this group's partial min per query
    float* om = mins + ((size_t)((dir * BATCH + b) * GROUPS + g)) * NPTS +
                qb * QPB + threadIdx.x;
    om[0 * BLOCK] = fmaxf(sp0 + best0, 0.0f);
    om[1 * BLOCK] = fmaxf(sp1 + best1, 0.0f);
    om[2 * BLOCK] = fmaxf(sp2 + best2, 0.0f);
    om[3 * BLOCK] = fmaxf(sp3 + best3, 0.0f);
}

// ---------------------------------------------------------------------------
// finalize: 64 blocks x 256 threads. Each thread owns 4 adjacent queries of
// one (dir,b) slice: min-reduces the 16 group partials (float4 loads,
// coalesced within each group slice), sums the 4 mins * 1/(B*N) -- the
// exact same sum tree as before. gid 0 adds the regularizer. Block reduce
// + atomicAdd into out[0].
// ---------------------------------------------------------------------------
__global__ __launch_bounds__(256) void finalize_kernel(
    const float* __restrict__ mins, const float* __restrict__ R,
    const float* __restrict__ S, const float* __restrict__ t,
    const float* __restrict__ R_gt, const float* __restrict__ S_gt,
    const float* __restrict__ t_gt, float* __restrict__ out) {
    const float4* m4 = (const float4*)mins;  // [8][GROUPS][NPTS/4]
    const int gid = blockIdx.x * 256 + (int)threadIdx.x;  // 0..16383
    const int db = gid >> 11;       // dir*BATCH+b, 0..7
    const int qi = gid & 2047;      // float4 index within slice

    float4 mn = m4[(size_t)(db * GROUPS) * (NPTS / 4) + qi];
#pragma unroll
    for (int gg = 1; gg < GROUPS; ++gg) {
        const float4 u = m4[(size_t)(db * GROUPS + gg) * (NPTS / 4) + qi];
        mn.x = fminf(mn.x, u.x);
        mn.y = fminf(mn.y, u.y);
        mn.z = fminf(mn.z, u.z);
        mn.w = fminf(mn.w, u.w);
    }
    float v = (mn.x + mn.y + mn.z + mn.w) * (1.0f / (BATCH * NPTS));

    if (gid == 0) {
        float acc = 0.0f;
        for (int b = 0; b < BATCH; ++b)
            for (int i = 0; i < 3; ++i)
                for (int k = 0; k < 3; ++k) {
                    float s = 0.0f;
                    for (int j = 0; j < 3; ++j)
                        s += R_gt[b * 9 + j * 3 + i] * R[b * 9 + j * 3 + k];
                    s -= (i == k) ? 1.0f : 0.0f;
                    acc += s * s;
                }
        for (int d = 0; d < 3; ++d)  // jnp.diagonal(S, axis1=0, axis2=1)
            for (int a = 0; a < 3; ++a) {
                const float diff = S[d * 9 + d * 3 + a] - S_gt[d * 9 + d * 3 + a];
                acc += diff * diff;
            }
        for (int b = 0; b < BATCH; ++b)
            for (int k = 0; k < 3; ++k) {
                const float diff = t[b * 3 + k] - t_gt[b * 3 + k];
                acc += diff * diff;
            }
        v += acc;
    }

    // block reduction: 4 waves of 64
    for (int off = 32; off; off >>= 1) v += __shfl_down(v, off, 64);
    __shared__ float wsum[4];
    const int lane = threadIdx.x & 63;
    const int wave = threadIdx.x >> 6;
    if (lane == 0) wsum[wave] = v;
    __syncthreads();
    if (wave == 0) {
        v = (lane < 4) ? wsum[lane] : 0.0f;
        for (int off = 2; off; off >>= 1) v += __shfl_down(v, off, 64);
        if (lane == 0) atomicAdd(out, v);
    }
}

extern "C" void kernel_launch(void* const* d_in, const int* in_sizes, int n_in,
                              void* d_out, int out_size, void* d_ws, size_t ws_size,
                              hipStream_t stream) {
    const float* x    = (const float*)d_in[0];
    const float* y    = (const float*)d_in[1];
    const float* R    = (const float*)d_in[2];
    const float* S    = (const float*)d_in[3];
    const float* t    = (const float*)d_in[4];
    const float* R_gt = (const float*)d_in[5];
    const float* S_gt = (const float*)d_in[6];
    const float* t_gt = (const float*)d_in[7];
    float* out = (float*)d_out;
    float* mins = (float*)d_ws;  // 2*BATCH*GROUPS*NPTS floats = 4 MiB

    chamfer_kernel<<<dim3(QBLOCKS * GROUPS, BATCH, 2), dim3(BLOCK), 0, stream>>>(
        x, y, mins, out);

    finalize_kernel<<<dim3(2 * BATCH * NPTS / 4 / 256), dim3(BLOCK), 0, stream>>>(
        mins, R, S, t, R_gt, S_gt, t_gt, out);
}